// Round 6
// baseline (358.653 us; speedup 1.0000x reference)
//
#include <hip/hip_runtime.h>
#include <stdint.h>

#define T_TOK 16384
#define D_DIM 1024
#define E_NUM 8
#define NTILE 136          // 256-row tiles: ceil-sum bound 135, padded

typedef __attribute__((ext_vector_type(4))) float f32x4;
typedef __attribute__((ext_vector_type(8))) __bf16 bf16x8;
typedef __attribute__((ext_vector_type(4))) unsigned short u16x4;
typedef const __attribute__((address_space(1))) void* gas_ptr;
typedef __attribute__((address_space(3))) void* las_ptr;

// ---- ws layout (ws_size >= 69,730,304 proven in round 1) ----
#define WS_Y     0ULL                      // bf16 Y[32768][1024] = 67,108,864
#define WS_ATOK  67108864ULL               // int[32768]  (value = 2*token + k)
#define WS_AW    (WS_ATOK + 131072ULL)     // float[32768]
#define WS_SCHED (WS_AW + 131072ULL)       // int4[136] (2304 reserved)
#define WS_TKI   (WS_SCHED + 2304ULL)      // int[2*16384] = 131072
#define WS_TKWH  (WS_TKI + 131072ULL)      // ushort bf16[2*16384] = 65536
#define WS_WOB   (WS_TKWH + 65536ULL)      // bf16[1024][1024] = 2,097,152 (ends 69,667,072)

// ---- d_out layout during compute (fully overwritten by k_outproj at the end) ----
// Xb  bf16[16384][1024] at +0          (33,554,432 B)
// Web bf16[8][1024][1024] at +33554432 (16,777,216 B)

__device__ __forceinline__ unsigned short f2b(float f){
  unsigned int u = __float_as_uint(f);
  u = (u + 0x7FFFu + ((u >> 16) & 1u)) >> 16;   // RNE bf16
  return (unsigned short)u;
}
__device__ __forceinline__ float b2f(unsigned short u){
  return __uint_as_float(((unsigned int)u) << 16);
}

// ---------------- K1: fused router (X->bf16 + top2) / We->bf16 / Wo->bf16 ----------------
// grid: [0,4096) router (4 tokens/block), [4096,12288) cvt We, [12288,13312) cvt Wo
__global__ __launch_bounds__(256) void k_prep(const float* __restrict__ X,
    const float* __restrict__ Wr, const float* __restrict__ br,
    const float* __restrict__ We, const float* __restrict__ Wo,
    unsigned short* __restrict__ Xb, unsigned short* __restrict__ Web,
    unsigned short* __restrict__ Wob, int* __restrict__ tki, unsigned short* __restrict__ tkwh)
{
  const int bid = blockIdx.x;
  if (bid < 4096){
    const int wv = threadIdx.x >> 6, lane = threadIdx.x & 63;
    const int t = bid * 4 + wv;
    const float* x = X + (size_t)t * D_DIM;
    unsigned short* xb = Xb + (size_t)t * D_DIM;
    float acc[E_NUM] = {};
    #pragma unroll
    for (int c = 0; c < 4; ++c){
      const int d = c * 256 + lane * 4;
      f32x4 xv = *reinterpret_cast<const f32x4*>(x + d);
      u16x4 o;
      o[0]=f2b(xv[0]); o[1]=f2b(xv[1]); o[2]=f2b(xv[2]); o[3]=f2b(xv[3]);
      *reinterpret_cast<u16x4*>(xb + d) = o;
      #pragma unroll
      for (int e = 0; e < E_NUM; ++e){
        f32x4 w4 = *reinterpret_cast<const f32x4*>(Wr + e * D_DIM + d);
        acc[e] += xv[0]*w4[0] + xv[1]*w4[1] + xv[2]*w4[2] + xv[3]*w4[3];
      }
    }
    #pragma unroll
    for (int e = 0; e < E_NUM; ++e){
      float v = acc[e];
      #pragma unroll
      for (int off = 32; off >= 1; off >>= 1) v += __shfl_xor(v, off, 64);
      acc[e] = v + br[e];
    }
    int i1 = 0; float l1 = acc[0];
    #pragma unroll
    for (int e = 1; e < E_NUM; ++e) if (acc[e] > l1){ l1 = acc[e]; i1 = e; }
    int i2 = -1; float l2 = -3.4e38f;
    #pragma unroll
    for (int e = 0; e < E_NUM; ++e) if (e != i1 && acc[e] > l2){ l2 = acc[e]; i2 = e; }
    float s = 0.f;
    #pragma unroll
    for (int e = 0; e < E_NUM; ++e) s += __expf(acc[e] - l1);
    if (lane == 0){
      tki[2*t] = i1; tki[2*t+1] = i2;
      tkwh[2*t] = f2b(1.0f / s); tkwh[2*t+1] = f2b(__expf(l2 - l1) / s);
    }
  } else if (bid < 12288){
    const int i = (bid - 4096) * 256 + threadIdx.x;     // n4 = 2,097,152
    f32x4 v = reinterpret_cast<const f32x4*>(We)[i];
    u16x4 o;
    o[0]=f2b(v[0]); o[1]=f2b(v[1]); o[2]=f2b(v[2]); o[3]=f2b(v[3]);
    reinterpret_cast<u16x4*>(Web)[i] = o;
  } else {
    const int i = (bid - 12288) * 256 + threadIdx.x;    // n4 = 262,144
    f32x4 v = reinterpret_cast<const f32x4*>(Wo)[i];
    u16x4 o;
    o[0]=f2b(v[0]); o[1]=f2b(v[1]); o[2]=f2b(v[2]); o[3]=f2b(v[3]);
    reinterpret_cast<u16x4*>(Wob)[i] = o;
  }
}

// ---------------- K2: hist + scan + scatter in ONE block (1024 thr, 16 waves) ----------------
__global__ __launch_bounds__(1024) void k_sched2(const int* __restrict__ tki,
    const unsigned short* __restrict__ tkwh, int4* __restrict__ sched,
    int* __restrict__ atok, float* __restrict__ aw)
{
  __shared__ int cnts[256][E_NUM];
  __shared__ int bases[256][E_NUM];
  const int tid = threadIdx.x, wv = tid >> 6, lane = tid & 63;

  // phase 1: per-64-token-group per-expert counts (wave w owns groups w*16..w*16+15)
  #pragma unroll 1
  for (int i = 0; i < 16; ++i){
    const int g = wv * 16 + i;
    const int t = g * 64 + lane;
    const int e0 = tki[2*t], e1 = tki[2*t+1];
    #pragma unroll
    for (int ex = 0; ex < E_NUM; ++ex){
      unsigned long long m0 = __ballot(e0 == ex);
      unsigned long long m1 = __ballot(e1 == ex);
      if (lane == 0) cnts[g][ex] = __popcll(m0) + __popcll(m1);
    }
  }
  __syncthreads();

  // phase 2: scan (wave 0): bases[g][e] = expert offset + prefix over groups
  if (wv == 0){
    const int e = lane & 7, g8 = lane >> 3;    // 8 super-groups x 32 groups
    int own = 0;
    #pragma unroll 1
    for (int i = 0; i < 32; ++i) own += cnts[g8 * 32 + i][e];
    int incl = own;
    #pragma unroll
    for (int s = 8; s < 64; s <<= 1){
      int v = __shfl_up(incl, s, 64);
      if (lane >= s) incl += v;
    }
    int tot[E_NUM];
    #pragma unroll
    for (int ee = 0; ee < E_NUM; ++ee) tot[ee] = __shfl(incl, 56 + ee, 64);
    int offs_e = 0;
    #pragma unroll
    for (int ee = 0; ee < E_NUM; ++ee) if (ee < e) offs_e += tot[ee];
    int run = offs_e + (incl - own);
    #pragma unroll 1
    for (int i = 0; i < 32; ++i){
      const int b = g8 * 32 + i;
      bases[b][e] = run;
      run += cnts[b][e];
    }
    if (lane == 0){
      int slot = 0, off = 0;
      for (int ee = 0; ee < E_NUM; ++ee){
        const int c = tot[ee];
        for (int tile = 0; tile * 256 < c && slot < NTILE; ++tile)
          sched[slot++] = make_int4(ee, off + tile * 256, min(256, c - tile * 256), 0);
        off += c;
      }
      while (slot < NTILE) sched[slot++] = make_int4(0, 0, 0, 0);
    }
  }
  __syncthreads();

  // phase 3: scatter via deterministic ballot ranks
  #pragma unroll 1
  for (int i = 0; i < 16; ++i){
    const int g = wv * 16 + i;
    const int t = g * 64 + lane;
    const unsigned long long lt = (1ull << lane) - 1ull;
    const int e0 = tki[2*t], e1 = tki[2*t+1];
    int r0 = 0, r1 = 0, p0c[E_NUM];
    #pragma unroll
    for (int ex = 0; ex < E_NUM; ++ex){
      unsigned long long m0 = __ballot(e0 == ex);
      p0c[ex] = __popcll(m0);
      if (e0 == ex) r0 = __popcll(m0 & lt);
    }
    #pragma unroll
    for (int ex = 0; ex < E_NUM; ++ex){
      unsigned long long m1 = __ballot(e1 == ex);
      if (e1 == ex) r1 = p0c[ex] + __popcll(m1 & lt);
    }
    const int row0 = bases[g][e0] + r0;
    const int row1 = bases[g][e1] + r1;
    atok[row0] = 2*t;     aw[row0] = b2f(tkwh[2*t]);
    atok[row1] = 2*t + 1; aw[row1] = b2f(tkwh[2*t+1]);
  }
}

// ---------------- expert gather-GEMM, 512 thr / 8 waves, 256x128 tile ----------------
__global__ __launch_bounds__(512, 4) void k_expert(const unsigned short* __restrict__ Xb,
    const unsigned short* __restrict__ Web, const float* __restrict__ be,
    const int4* __restrict__ sched, const int* __restrict__ atok,
    const float* __restrict__ aw, unsigned short* __restrict__ Y)
{
  __shared__ unsigned short As[256 * 64];   // 32 KB
  __shared__ unsigned short Bs[128 * 64];   // 16 KB
  __shared__ int   tok_s[256];
  __shared__ float w_s[256];

  const int lin = blockIdx.x;             // [0, 1088)
  const int x = lin & 7, c = (lin >> 3) & 7, a = lin >> 6;   // a in [0,17)
  const int j = x * 17 + a;               // bijective: 136 = 8*17
  const int4 sc = sched[j];
  const int e = sc.x, row0 = sc.y, nval = sc.z;
  if (nval == 0) return;                  // filler slot: uniform early exit (before any barrier)
  const int n0 = c * 128;

  const int tid = threadIdx.x, wv = tid >> 6, lane = tid & 63;
  const int wm = wv >> 1, wn = wv & 1, lr = lane & 15, lg = lane >> 4;

  if (tid < 256){
    tok_s[tid] = atok[row0 + max(0, min(tid, nval - 1))];
    w_s[tid]   = aw[row0 + min(tid, 255)];           // tail garbage guarded below
  }
  __syncthreads();

  const char* asrc[4]; const char* bsrc[2]; int ldsoA[4], ldsoB[2];
  #pragma unroll
  for (int i = 0; i < 4; ++i){
    const int chunk = i * 8 + wv;                 // 32 x 1KB (A)
    const int byte0 = chunk * 1024 + lane * 16;
    const int r = byte0 >> 7;                     // tile row [0,256)
    const int scb = (byte0 & 127) ^ ((r & 7) << 4);
    asrc[i] = (const char*)(Xb + (size_t)(tok_s[r] >> 1) * D_DIM) + scb;
    ldsoA[i] = chunk * 512;
  }
  #pragma unroll
  for (int i = 0; i < 2; ++i){
    const int chunk = i * 8 + wv;                 // 16 x 1KB (B)
    const int byte0 = chunk * 1024 + lane * 16;
    const int r = byte0 >> 7;                     // [0,128)
    const int scb = (byte0 & 127) ^ ((r & 7) << 4);
    bsrc[i] = (const char*)(Web + ((size_t)e * D_DIM + n0 + r) * D_DIM) + scb;
    ldsoB[i] = chunk * 512;
  }

  f32x4 acc[4][4] = {};
  #pragma unroll 1
  for (int kt = 0; kt < 16; ++kt){
    __syncthreads();
    #pragma unroll
    for (int i = 0; i < 4; ++i)
      __builtin_amdgcn_global_load_lds((gas_ptr)(asrc[i] + kt * 128), (las_ptr)(As + ldsoA[i]), 16, 0, 0);
    #pragma unroll
    for (int i = 0; i < 2; ++i)
      __builtin_amdgcn_global_load_lds((gas_ptr)(bsrc[i] + kt * 128), (las_ptr)(Bs + ldsoB[i]), 16, 0, 0);
    __syncthreads();
    #pragma unroll
    for (int kk = 0; kk < 2; ++kk){
      bf16x8 af[4], bfr[4];
      #pragma unroll
      for (int fm = 0; fm < 4; ++fm){
        const int r = wm*64 + fm*16 + lr;
        af[fm] = *reinterpret_cast<const bf16x8*>((char*)As + ((r*128 + kk*64 + lg*16) ^ ((r & 7) << 4)));
      }
      #pragma unroll
      for (int fn = 0; fn < 4; ++fn){
        const int r = wn*64 + fn*16 + lr;
        bfr[fn] = *reinterpret_cast<const bf16x8*>((char*)Bs + ((r*128 + kk*64 + lg*16) ^ ((r & 7) << 4)));
      }
      #pragma unroll
      for (int fm = 0; fm < 4; ++fm)
        #pragma unroll
        for (int fn = 0; fn < 4; ++fn)
          acc[fm][fn] = __builtin_amdgcn_mfma_f32_16x16x32_bf16(af[fm], bfr[fn], acc[fm][fn], 0, 0, 0);
    }
  }

  float bev[4];
  #pragma unroll
  for (int fn = 0; fn < 4; ++fn) bev[fn] = be[e * D_DIM + n0 + wn*64 + fn*16 + lr];
  #pragma unroll
  for (int fm = 0; fm < 4; ++fm){
    #pragma unroll
    for (int jj = 0; jj < 4; ++jj){
      const int r = wm*64 + fm*16 + lg*4 + jj;
      if (r < nval){
        const float w = w_s[r];
        const size_t yrow = (size_t)tok_s[r];     // 2*t + k
        #pragma unroll
        for (int fn = 0; fn < 4; ++fn){
          const int col = n0 + wn*64 + fn*16 + lr;
          Y[yrow * D_DIM + col] = f2b(w * (acc[fm][fn][jj] + bev[fn]));
        }
      }
    }
  }
}

// ---------------- out-proj, 512 thr / 8 waves, 256-token tile, dual-A MFMA ----------------
__global__ __launch_bounds__(512, 4) void k_outproj(const unsigned short* __restrict__ Y,
    const unsigned short* __restrict__ Wob, const float* __restrict__ bo,
    float* __restrict__ out)
{
  __shared__ unsigned short As0[256 * 64];  // 32 KB
  __shared__ unsigned short As1[256 * 64];  // 32 KB
  __shared__ unsigned short Bs[128 * 64];   // 16 KB

  const int lin = blockIdx.x;             // [0, 512)
  const int x = lin & 7, c = (lin >> 3) & 7, a = lin >> 6;   // a in [0,8)
  const int tm = x * 8 + a;               // bijective: 64 = 8*8
  const int n0 = c * 128;

  const int tid = threadIdx.x, wv = tid >> 6, lane = tid & 63;
  const int wm = wv >> 1, wn = wv & 1, lr = lane & 15, lg = lane >> 4;

  const char* a0src[4]; const char* a1src[4]; const char* bsrc[2]; int ldsoA[4], ldsoB[2];
  #pragma unroll
  for (int i = 0; i < 4; ++i){
    const int chunk = i * 8 + wv;
    const int byte0 = chunk * 1024 + lane * 16;
    const int r = byte0 >> 7;                     // [0,256)
    const int scb = (byte0 & 127) ^ ((r & 7) << 4);
    const size_t t = (size_t)(tm * 256 + r);
    a0src[i] = (const char*)(Y + (2*t)     * D_DIM) + scb;
    a1src[i] = (const char*)(Y + (2*t + 1) * D_DIM) + scb;
    ldsoA[i] = chunk * 512;
  }
  #pragma unroll
  for (int i = 0; i < 2; ++i){
    const int chunk = i * 8 + wv;
    const int byte0 = chunk * 1024 + lane * 16;
    const int r = byte0 >> 7;                     // [0,128)
    const int scb = (byte0 & 127) ^ ((r & 7) << 4);
    bsrc[i] = (const char*)(Wob + (size_t)(n0 + r) * D_DIM) + scb;
    ldsoB[i] = chunk * 512;
  }

  f32x4 acc[4][4] = {};
  #pragma unroll 1
  for (int kt = 0; kt < 16; ++kt){
    __syncthreads();
    #pragma unroll
    for (int i = 0; i < 4; ++i){
      __builtin_amdgcn_global_load_lds((gas_ptr)(a0src[i] + kt * 128), (las_ptr)(As0 + ldsoA[i]), 16, 0, 0);
      __builtin_amdgcn_global_load_lds((gas_ptr)(a1src[i] + kt * 128), (las_ptr)(As1 + ldsoA[i]), 16, 0, 0);
    }
    #pragma unroll
    for (int i = 0; i < 2; ++i)
      __builtin_amdgcn_global_load_lds((gas_ptr)(bsrc[i] + kt * 128), (las_ptr)(Bs + ldsoB[i]), 16, 0, 0);
    __syncthreads();
    #pragma unroll
    for (int kk = 0; kk < 2; ++kk){
      bf16x8 a0f[4], a1f[4], bfr[4];
      #pragma unroll
      for (int fm = 0; fm < 4; ++fm){
        const int r = wm*64 + fm*16 + lr;
        const int ba = (r*128 + kk*64 + lg*16) ^ ((r & 7) << 4);
        a0f[fm] = *reinterpret_cast<const bf16x8*>((char*)As0 + ba);
        a1f[fm] = *reinterpret_cast<const bf16x8*>((char*)As1 + ba);
      }
      #pragma unroll
      for (int fn = 0; fn < 4; ++fn){
        const int r = wn*64 + fn*16 + lr;
        bfr[fn] = *reinterpret_cast<const bf16x8*>((char*)Bs + ((r*128 + kk*64 + lg*16) ^ ((r & 7) << 4)));
      }
      #pragma unroll
      for (int fm = 0; fm < 4; ++fm)
        #pragma unroll
        for (int fn = 0; fn < 4; ++fn){
          acc[fm][fn] = __builtin_amdgcn_mfma_f32_16x16x32_bf16(a0f[fm], bfr[fn], acc[fm][fn], 0, 0, 0);
          acc[fm][fn] = __builtin_amdgcn_mfma_f32_16x16x32_bf16(a1f[fm], bfr[fn], acc[fm][fn], 0, 0, 0);
        }
    }
  }

  float bov[4];
  #pragma unroll
  for (int fn = 0; fn < 4; ++fn) bov[fn] = bo[n0 + wn*64 + fn*16 + lr];
  #pragma unroll
  for (int fm = 0; fm < 4; ++fm){
    #pragma unroll
    for (int jj = 0; jj < 4; ++jj){
      const int r = wm*64 + fm*16 + lg*4 + jj;
      #pragma unroll
      for (int fn = 0; fn < 4; ++fn){
        const int col = n0 + wn*64 + fn*16 + lr;
        out[(size_t)(tm * 256 + r) * D_DIM + col] = acc[fm][fn][jj] + bov[fn];
      }
    }
  }
}

extern "C" void kernel_launch(void* const* d_in, const int* in_sizes, int n_in,
                              void* d_out, int out_size, void* d_ws, size_t ws_size,
                              hipStream_t stream)
{
  const float* X  = (const float*)d_in[0];
  const float* We = (const float*)d_in[1];
  const float* be = (const float*)d_in[2];
  const float* Wr = (const float*)d_in[3];
  const float* br = (const float*)d_in[4];
  const float* Wo = (const float*)d_in[5];
  const float* bo = (const float*)d_in[6];
  float* out = (float*)d_out;
  char* ws = (char*)d_ws;

  unsigned short* Y    = (unsigned short*)(ws + WS_Y);
  int*            atok = (int*)(ws + WS_ATOK);
  float*          aw   = (float*)(ws + WS_AW);
  int4*           sched= (int4*)(ws + WS_SCHED);
  int*            tki  = (int*)(ws + WS_TKI);
  unsigned short* tkwh = (unsigned short*)(ws + WS_TKWH);
  unsigned short* Wob  = (unsigned short*)(ws + WS_WOB);

  unsigned short* Xb  = (unsigned short*)d_out;                       // 33.5 MB
  unsigned short* Web = (unsigned short*)((char*)d_out + 33554432);   // 16.8 MB (both dead before out write)

  k_prep<<<13312, 256, 0, stream>>>(X, Wr, br, We, Wo, Xb, Web, Wob, tki, tkwh);
  k_sched2<<<1, 1024, 0, stream>>>(tki, tkwh, sched, atok, aw);
  k_expert<<<NTILE * 8, 512, 0, stream>>>(Xb, Web, be, sched, atok, aw, Y);
  k_outproj<<<512, 512, 0, stream>>>(Y, Wob, bo, out);
}